// Round 7
// baseline (743.838 us; speedup 1.0000x reference)
//
#include <hip/hip_runtime.h>
#include <hip/hip_bf16.h>
#include <math.h>

#define CDIV(a,b) (((a)+(b)-1)/(b))

typedef __bf16  bf16x8 __attribute__((ext_vector_type(8)));
typedef float   f32x4  __attribute__((ext_vector_type(4)));
typedef unsigned short u16x8 __attribute__((ext_vector_type(8)));
typedef unsigned short u16x4 __attribute__((ext_vector_type(4)));

__device__ __forceinline__ float bf2f(unsigned short u) {
    union { unsigned int i; float f; } x; x.i = ((unsigned int)u) << 16; return x.f;
}
__device__ __forceinline__ unsigned short f2bf(float f) {
    union { float f; unsigned int i; } x; x.f = f;
    unsigned int r = x.i + 0x7fff + ((x.i >> 16) & 1);   // RNE, finite inputs
    return (unsigned short)(r >> 16);
}

// ---------------------------------------------------------------------------
// CSR build (by destination node). Edges = [E graph edges] + [n self-loops].
// ---------------------------------------------------------------------------
__global__ void hist_kernel(const int* __restrict__ ei, int* __restrict__ deg,
                            int E, int Et) {
    int e = blockIdx.x * blockDim.x + threadIdx.x;
    if (e >= Et) return;
    int d = (e < E) ? ei[E + e] : (e - E);
    atomicAdd(&deg[d], 1);
}

// Single-block exclusive scan, wave-shuffle based.
__global__ void scan_kernel(const int* __restrict__ deg, int* __restrict__ off, int n) {
    __shared__ int wsum[16];
    __shared__ int carry_s;
    int t = threadIdx.x, lane = t & 63, wv = t >> 6;
    if (t == 0) carry_s = 0;
    __syncthreads();
    for (int base = 0; base < n; base += 1024) {
        int v = (base + t < n) ? deg[base + t] : 0;
        int x = v;
#pragma unroll
        for (int o = 1; o < 64; o <<= 1) {
            int y = __shfl_up(x, o);
            if (lane >= o) x += y;
        }
        if (lane == 63) wsum[wv] = x;
        __syncthreads();
        if (wv == 0 && lane < 16) {
            int s = wsum[lane];
#pragma unroll
            for (int o = 1; o < 16; o <<= 1) {
                int y = __shfl_up(s, o);
                if (lane >= o) s += y;
            }
            wsum[lane] = s;
        }
        __syncthreads();
        int wprev = (wv == 0) ? 0 : wsum[wv - 1];
        int incl = carry_s + wprev + x;
        if (base + t < n) off[base + t] = incl - v;
        __syncthreads();
        if (t == 1023) carry_s = incl;
        __syncthreads();
    }
    if (t == 0) off[n] = carry_s;
}

__global__ void scatter_kernel(const int* __restrict__ ei, const int* __restrict__ off,
                               int* __restrict__ cur, int* __restrict__ csr,
                               int E, int Et) {
    int e = blockIdx.x * blockDim.x + threadIdx.x;
    if (e >= Et) return;
    int s, d;
    if (e < E) { s = ei[e]; d = ei[E + e]; } else { s = e - E; d = s; }
    int pos = off[d] + atomicAdd(&cur[d], 1);
    csr[pos] = s;
}

// ---------------------------------------------------------------------------
// Fused weight transpose+cvt: 3 jobs in one launch, 32x32 tiles.
// job j: wt_j[N_j,K_j] <- bf16(w_j[K_j,N_j])
// ---------------------------------------------------------------------------
__global__ void prep_t_kernel(const float* __restrict__ wa, __hip_bfloat16* __restrict__ wta,
                              const float* __restrict__ wb, __hip_bfloat16* __restrict__ wtb,
                              const float* __restrict__ wc, __hip_bfloat16* __restrict__ wtc,
                              int t0, int t1, int t2) {   // tile-count prefixes
    __shared__ float tile[32][33];
    int bid = blockIdx.x;
    const float* w; __hip_bfloat16* wt; int K, N, r;
    if (bid < t0)      { w = wa; wt = wta; K = 512;  N = 2048; r = bid; }
    else if (bid < t1) { w = wb; wt = wtb; K = 2048; N = 2048; r = bid - t0; }
    else               { w = wc; wt = wtc; K = 2048; N = 1024; r = bid - t1; }
    (void)t2;
    int kt = K >> 5;
    int kb = (r % kt) * 32, nb = (r / kt) * 32;
    int tx = threadIdx.x & 31, ty = threadIdx.x >> 5;   // 256 threads
    for (int i = ty; i < 32; i += 8)
        tile[i][tx] = w[(size_t)(kb + i) * N + nb + tx];
    __syncthreads();
    for (int i = ty; i < 32; i += 8)
        wt[(size_t)(nb + i) * K + kb + tx] = __float2bfloat16(tile[tx][i]);
}

// Fused fp32->bf16 convert of proj_w then x (both sizes %4 == 0).
__global__ void cvt2_kernel(const float* __restrict__ a, __hip_bfloat16* __restrict__ ao,
                            int na4,
                            const float* __restrict__ b, __hip_bfloat16* __restrict__ bo,
                            int nb4) {
    int i = blockIdx.x * blockDim.x + threadIdx.x;
    const float* src; __hip_bfloat16* dst; int idx;
    if (i < na4) { src = a; dst = ao; idx = i * 4; }
    else if (i < na4 + nb4) { src = b; dst = bo; idx = (i - na4) * 4; }
    else return;
    float4 v = *(const float4*)(src + idx);
    dst[idx + 0] = __float2bfloat16(v.x);
    dst[idx + 1] = __float2bfloat16(v.y);
    dst[idx + 2] = __float2bfloat16(v.z);
    dst[idx + 3] = __float2bfloat16(v.w);
}

// b_eff[j] += partial over k-chunk of proj_b[k]*w1[k][j] (k-split, unrolled).
__global__ void beff_kernel(const float* __restrict__ pb, const float* __restrict__ w1,
                            float* __restrict__ beff, int N) {
    int j  = blockIdx.x * 256 + threadIdx.x;
    int k0 = blockIdx.y * 64;
    float s = 0.f;
#pragma unroll
    for (int k = 0; k < 64; k++)
        s = fmaf(pb[k0 + k], w1[(size_t)(k0 + k) * N + j], s);
    atomicAdd(&beff[j], s);
}

// ---------------------------------------------------------------------------
// bf16 MFMA GEMM: Cb[M,N] = bf16(A[M,K] @ BT[N,K]^T (+bias))
// + fused es/ed epilogue: es[row*H+head] += sum_col v*a_src[head][col&511]
// (butterfly over lm lanes, one fp32 atomicAdd per row per wave).
// XCD-aware 1-D swizzle (xcd = bid&7 owns contiguous x-stripe).
// ---------------------------------------------------------------------------
__device__ __forceinline__ void gload16(void* lds, const void* g) {
    __builtin_amdgcn_global_load_lds(
        (const __attribute__((address_space(1))) void*)g,
        (__attribute__((address_space(3))) void*)lds, 16, 0, 0);
}

__global__ __launch_bounds__(256) void gemm_bf16_kernel(
    const __hip_bfloat16* __restrict__ A,
    const __hip_bfloat16* __restrict__ BT,
    const float* __restrict__ bias,
    __hip_bfloat16* __restrict__ Cb,
    const float* __restrict__ a_src, const float* __restrict__ a_dst,
    float* __restrict__ es, float* __restrict__ ed, int H,
    int M, int N, int K, int MB, int NB, int XT)
{
    __shared__ __align__(16) __hip_bfloat16 As[128 * 32];
    __shared__ __align__(16) __hip_bfloat16 Bs[128 * 32];

    const int bid  = blockIdx.x;
    const int xcd  = bid & 7;
    const int slot = bid >> 3;
    const int x_sub = slot / NB;
    const int yb    = slot - x_sub * NB;
    const int xb    = xcd * XT + x_sub;
    if (xb >= MB) return;

    const int tid = threadIdx.x;
    const int m0 = xb * 128, n0 = yb * 128;
    const int w = tid >> 6, l = tid & 63;
    const int wm = (w & 1) * 64, wn = (w >> 1) * 64;
    const int lm = l & 15, lq = l >> 4;

    f32x4 acc[4][4] = {};

    const int arow = tid >> 2;
    const int acol = (tid & 3) * 8;
    const __hip_bfloat16* Ag = A  + (size_t)(m0 + arow) * K + acol;
    const __hip_bfloat16* Bg = BT + (size_t)(n0 + arow) * K + acol;
    char* AsW = (char*)As + (w << 10);
    char* BsW = (char*)Bs + (w << 10);

    for (int k0 = 0; k0 < K; k0 += 32) {
        gload16(AsW,        Ag + k0);
        gload16(AsW + 4096, Ag + (size_t)64 * K + k0);
        gload16(BsW,        Bg + k0);
        gload16(BsW + 4096, Bg + (size_t)64 * K + k0);
        __syncthreads();
        bf16x8 af[4], bfr[4];
#pragma unroll
        for (int i = 0; i < 4; i++)
            af[i] = *(const bf16x8*)(As + (wm + i * 16 + lm) * 32 + lq * 8);
#pragma unroll
        for (int j = 0; j < 4; j++)
            bfr[j] = *(const bf16x8*)(Bs + (wn + j * 16 + lm) * 32 + lq * 8);
#pragma unroll
        for (int i = 0; i < 4; i++)
#pragma unroll
            for (int j = 0; j < 4; j++)
                acc[i][j] = __builtin_amdgcn_mfma_f32_16x16x32_bf16(
                    af[i], bfr[j], acc[i][j], 0, 0, 0);
        __syncthreads();
    }

    // per-lane attention-vector values for this wave's 4 columns
    const int head = (n0 + wn) >> 9;
    float as_[4], ad_[4];
    if (a_src) {
        int cb = ((n0 + wn) & 511) + lm;
#pragma unroll
        for (int j = 0; j < 4; j++) {
            as_[j] = a_src[head * 512 + cb + j * 16];
            ad_[j] = a_dst[head * 512 + cb + j * 16];
        }
    }

#pragma unroll
    for (int i = 0; i < 4; i++) {
#pragma unroll
        for (int r = 0; r < 4; r++) {
            int row = m0 + wm + i * 16 + lq * 4 + r;
            bool valid = row < M;
            float v[4];
#pragma unroll
            for (int j = 0; j < 4; j++) {
                v[j] = acc[i][j][r];
                if (bias) v[j] += bias[n0 + wn + j * 16 + lm];
            }
            if (valid) {
#pragma unroll
                for (int j = 0; j < 4; j++)
                    Cb[(size_t)row * N + n0 + wn + j * 16 + lm] = __float2bfloat16(v[j]);
            }
            if (a_src) {
                float se = v[0] * as_[0] + v[1] * as_[1] + v[2] * as_[2] + v[3] * as_[3];
                float de = v[0] * ad_[0] + v[1] * ad_[1] + v[2] * ad_[2] + v[3] * ad_[3];
#pragma unroll
                for (int o = 1; o < 16; o <<= 1) {
                    se += __shfl_xor(se, o);
                    de += __shfl_xor(de, o);
                }
                if (lm == 0 && valid) {
                    atomicAdd(&es[row * H + head], se);
                    atomicAdd(&ed[row * H + head], de);
                }
            }
        }
    }
}

// ---------------------------------------------------------------------------
// Aggregation: ONE block per dst, all heads. Thread t owns channels
// [t*VEC, t*VEC+VEC). 4x edge unroll. MEAN variant fuses head-mean + bias.
// ---------------------------------------------------------------------------
template<int H, int VEC, bool MEAN>
__global__ __launch_bounds__(256) void agg_kernel(
    const __hip_bfloat16* __restrict__ h, const float* __restrict__ es,
    const float* __restrict__ ed, const int* __restrict__ csr,
    const int* __restrict__ off, const float* __restrict__ bias,
    float* __restrict__ outF, __hip_bfloat16* __restrict__ outB, int do_elu)
{
    constexpr int HS = H * 512;
    __shared__ float red[MEAN ? 1024 : 1];
    int d = blockIdx.x, t = threadIdx.x;
    int c0 = t * VEC;
    int head = c0 >> 9;
    float edd = ed[d * H + head];
    int beg = off[d], end = off[d + 1];
    float acc[VEC];
#pragma unroll
    for (int k = 0; k < VEC; k++) acc[k] = 0.f;
    float den = 0.f;
    const unsigned short* hb = (const unsigned short*)h;

    int i = beg;
    for (; i + 3 < end; i += 4) {
        int   s[4];
        float wgt[4];
#pragma unroll
        for (int u = 0; u < 4; u++) {
            s[u] = csr[i + u];
            float e = es[s[u] * H + head] + edd;
            e = (e > 0.f) ? e : 0.2f * e;
            wgt[u] = __expf(e);
        }
        if constexpr (VEC == 8) {
            u16x8 v[4];
#pragma unroll
            for (int u = 0; u < 4; u++)
                v[u] = *(const u16x8*)(hb + (size_t)s[u] * HS + c0);
#pragma unroll
            for (int u = 0; u < 4; u++) {
                den += wgt[u];
#pragma unroll
                for (int k = 0; k < 8; k++) acc[k] = fmaf(wgt[u], bf2f(v[u][k]), acc[k]);
            }
        } else {
            u16x4 v[4];
#pragma unroll
            for (int u = 0; u < 4; u++)
                v[u] = *(const u16x4*)(hb + (size_t)s[u] * HS + c0);
#pragma unroll
            for (int u = 0; u < 4; u++) {
                den += wgt[u];
#pragma unroll
                for (int k = 0; k < VEC; k++) acc[k] = fmaf(wgt[u], bf2f(v[u][k]), acc[k]);
            }
        }
    }
    for (; i < end; i++) {
        int s0 = csr[i];
        float e0 = es[s0 * H + head] + edd;
        e0 = (e0 > 0.f) ? e0 : 0.2f * e0;
        float w0 = __expf(e0);
        den += w0;
        const unsigned short* hp0 = hb + (size_t)s0 * HS + c0;
        if constexpr (VEC == 8) {
            u16x8 v0 = *(const u16x8*)hp0;
#pragma unroll
            for (int k = 0; k < 8; k++) acc[k] = fmaf(w0, bf2f(v0[k]), acc[k]);
        } else {
            u16x4 v0 = *(const u16x4*)hp0;
#pragma unroll
            for (int k = 0; k < VEC; k++) acc[k] = fmaf(w0, bf2f(v0[k]), acc[k]);
        }
    }

    float inv = 1.f / den;
    if constexpr (!MEAN) {
        u16x8 ov;
#pragma unroll
        for (int k = 0; k < VEC; k++) {
            float v = acc[k] * inv + bias[c0 + k];
            if (do_elu) v = (v > 0.f) ? v : expm1f(v);
            ov[k] = f2bf(v);
        }
        *(u16x8*)((unsigned short*)outB + (size_t)d * HS + c0) = ov;
    } else {
#pragma unroll
        for (int k = 0; k < VEC; k++) red[c0 + k] = acc[k] * inv;
        __syncthreads();
        if (t < 128) {
#pragma unroll
            for (int k = 0; k < 4; k++) {
                int c = t * 4 + k;
                outF[(size_t)d * 512 + c] = 0.5f * (red[c] + red[c + 512]) + bias[c];
            }
        }
    }
}

// ---------------------------------------------------------------------------
extern "C" void kernel_launch(void* const* d_in, const int* in_sizes, int n_in,
                              void* d_out, int out_size, void* d_ws, size_t ws_size,
                              hipStream_t stream) {
    const float* x      = (const float*)d_in[0];
    const int*   ei     = (const int*)  d_in[1];
    const float* proj_w = (const float*)d_in[2];
    const float* proj_b = (const float*)d_in[3];
    const float* w1  = (const float*)d_in[4];
    const float* as1 = (const float*)d_in[5];
    const float* ad1 = (const float*)d_in[6];
    const float* b1  = (const float*)d_in[7];
    const float* w2  = (const float*)d_in[8];
    const float* as2 = (const float*)d_in[9];
    const float* ad2 = (const float*)d_in[10];
    const float* b2  = (const float*)d_in[11];
    const float* w3  = (const float*)d_in[12];
    const float* as3 = (const float*)d_in[13];
    const float* ad3 = (const float*)d_in[14];
    const float* b3  = (const float*)d_in[15];

    const int n    = in_sizes[0] / 256;   // 10000
    const int E    = in_sizes[1] / 2;     // 160000
    const int Et   = E + n;               // 170000
    const int MB   = CDIV(n, 128);        // 79
    const int Mpad = MB * 128;            // 10112
    const int XT   = CDIV(MB, 8);         // 10

    char* p = (char*)d_ws;
    auto carve = [&](size_t bytes) {
        void* r = (void*)p;
        p += (bytes + 255) & ~(size_t)255;
        return r;
    };
    __hip_bfloat16* h_bf    = (__hip_bfloat16*)carve((size_t)Mpad * 2048 * sizeof(__hip_bfloat16));
    __hip_bfloat16* act_bf  = (__hip_bfloat16*)carve((size_t)Mpad * 2048 * sizeof(__hip_bfloat16));
    __hip_bfloat16* x_bf    = (__hip_bfloat16*)carve((size_t)Mpad * 256 * sizeof(__hip_bfloat16));
    __hip_bfloat16* pw_bf   = (__hip_bfloat16*)carve((size_t)256 * 512 * sizeof(__hip_bfloat16));
    __hip_bfloat16* w1t     = (__hip_bfloat16*)carve((size_t)2048 * 512 * sizeof(__hip_bfloat16));
    __hip_bfloat16* w2t     = (__hip_bfloat16*)carve((size_t)2048 * 2048 * sizeof(__hip_bfloat16));
    __hip_bfloat16* w3t     = (__hip_bfloat16*)carve((size_t)1024 * 2048 * sizeof(__hip_bfloat16));
    __hip_bfloat16* w_efft  = (__hip_bfloat16*)carve((size_t)2048 * 256 * sizeof(__hip_bfloat16));
    float* b_eff = (float*)carve((size_t)2048 * sizeof(float));
    float* es  = (float*)carve((size_t)n * 4 * sizeof(float));   // n*16 B, 256-aligned
    float* ed  = (float*)carve((size_t)n * 4 * sizeof(float));   // contiguous after es
    int* deg = (int*)carve((size_t)2 * n * sizeof(int));         // deg + cur contiguous
    int* cur = deg + n;
    int* off = (int*)carve((size_t)(n + 1) * sizeof(int));
    int* csr = (int*)carve((size_t)Et * sizeof(int));
    (void)ws_size; (void)n_in;

    // --- CSR build ---
    hipMemsetAsync(deg, 0, 2 * n * sizeof(int), stream);
    hipMemsetAsync(b_eff, 0, 2048 * sizeof(float), stream);
    hist_kernel<<<CDIV(Et, 256), 256, 0, stream>>>(ei, deg, E, Et);
    scan_kernel<<<1, 1024, 0, stream>>>(deg, off, n);
    scatter_kernel<<<CDIV(Et, 256), 256, 0, stream>>>(ei, off, cur, csr, E, Et);

    // --- weight prep (fused) ---
    const int t0 = (512 / 32) * (2048 / 32);            // 1024
    const int t1 = t0 + (2048 / 32) * (2048 / 32);      // +4096
    const int t2 = t1 + (2048 / 32) * (1024 / 32);      // +2048
    prep_t_kernel<<<t2, 256, 0, stream>>>(w1, w1t, w2, w2t, w3, w3t, t0, t1, t2);
    const int na4 = 256 * 512 / 4, nb4 = n * 256 / 4;
    cvt2_kernel<<<CDIV(na4 + nb4, 256), 256, 0, stream>>>(proj_w, pw_bf, na4, x, x_bf, nb4);

    // --- fold proj into layer 1 ---
    gemm_bf16_kernel<<<8 * 2 * 2, 256, 0, stream>>>(
        w1t, pw_bf, nullptr, w_efft, nullptr, nullptr, nullptr, nullptr, 0,
        2048, 256, 512, 16, 2, 2);
    beff_kernel<<<dim3(2048 / 256, 512 / 64), 256, 0, stream>>>(proj_b, w1, b_eff, 2048);

    auto gemm_grid = [&](int NB) { return 8 * XT * NB; };

    // --- layer 1 (H=4, concat, ELU):  h = x @ W_eff + b_eff, es/ed fused ---
    hipMemsetAsync(es, 0, 2 * (size_t)n * 4 * sizeof(float), stream);
    gemm_bf16_kernel<<<gemm_grid(16), 256, 0, stream>>>(
        x_bf, w_efft, b_eff, h_bf, as1, ad1, es, ed, 4, n, 2048, 256, MB, 16, XT);
    agg_kernel<4, 8, false><<<n, 256, 0, stream>>>(h_bf, es, ed, csr, off, b1,
                                                   nullptr, act_bf, 1);

    // --- layer 2 (H=4, concat, ELU) ---
    hipMemsetAsync(es, 0, 2 * (size_t)n * 4 * sizeof(float), stream);
    gemm_bf16_kernel<<<gemm_grid(16), 256, 0, stream>>>(
        act_bf, w2t, nullptr, h_bf, as2, ad2, es, ed, 4, n, 2048, 2048, MB, 16, XT);
    agg_kernel<4, 8, false><<<n, 256, 0, stream>>>(h_bf, es, ed, csr, off, b2,
                                                   nullptr, act_bf, 1);

    // --- layer 3 (H=2, mean+bias fused, no ELU) ---
    hipMemsetAsync(es, 0, 2 * (size_t)n * 4 * sizeof(float), stream);
    gemm_bf16_kernel<<<gemm_grid(8), 256, 0, stream>>>(
        act_bf, w3t, nullptr, h_bf, as3, ad3, es, ed, 2, n, 1024, 2048, MB, 8, XT);
    agg_kernel<2, 4, true><<<n, 256, 0, stream>>>(h_bf, es, ed, csr, off, b3,
                                                  (float*)d_out, nullptr, 0);
}

// Round 8
// 667.027 us; speedup vs baseline: 1.1152x; 1.1152x over previous
//
#include <hip/hip_runtime.h>
#include <hip/hip_bf16.h>
#include <math.h>

#define CDIV(a,b) (((a)+(b)-1)/(b))

typedef __bf16  bf16x8 __attribute__((ext_vector_type(8)));
typedef float   f32x4  __attribute__((ext_vector_type(4)));
typedef unsigned short u16x8 __attribute__((ext_vector_type(8)));
typedef unsigned short u16x4 __attribute__((ext_vector_type(4)));

__device__ __forceinline__ float bf2f(unsigned short u) {
    union { unsigned int i; float f; } x; x.i = ((unsigned int)u) << 16; return x.f;
}
__device__ __forceinline__ unsigned short f2bf(float f) {
    union { float f; unsigned int i; } x; x.f = f;
    unsigned int r = x.i + 0x7fff + ((x.i >> 16) & 1);   // RNE, finite inputs
    return (unsigned short)(r >> 16);
}

// ---------------------------------------------------------------------------
// CSR build (by destination node). Edges = [E graph edges] + [n self-loops].
// ---------------------------------------------------------------------------
__global__ void hist_kernel(const int* __restrict__ ei, int* __restrict__ deg,
                            int E, int Et) {
    int e = blockIdx.x * blockDim.x + threadIdx.x;
    if (e >= Et) return;
    int d = (e < E) ? ei[E + e] : (e - E);
    atomicAdd(&deg[d], 1);
}

// Single-block exclusive scan, wave-shuffle based.
__global__ void scan_kernel(const int* __restrict__ deg, int* __restrict__ off, int n) {
    __shared__ int wsum[16];
    __shared__ int carry_s;
    int t = threadIdx.x, lane = t & 63, wv = t >> 6;
    if (t == 0) carry_s = 0;
    __syncthreads();
    for (int base = 0; base < n; base += 1024) {
        int v = (base + t < n) ? deg[base + t] : 0;
        int x = v;
#pragma unroll
        for (int o = 1; o < 64; o <<= 1) {
            int y = __shfl_up(x, o);
            if (lane >= o) x += y;
        }
        if (lane == 63) wsum[wv] = x;
        __syncthreads();
        if (wv == 0 && lane < 16) {
            int s = wsum[lane];
#pragma unroll
            for (int o = 1; o < 16; o <<= 1) {
                int y = __shfl_up(s, o);
                if (lane >= o) s += y;
            }
            wsum[lane] = s;
        }
        __syncthreads();
        int wprev = (wv == 0) ? 0 : wsum[wv - 1];
        int incl = carry_s + wprev + x;
        if (base + t < n) off[base + t] = incl - v;
        __syncthreads();
        if (t == 1023) carry_s = incl;
        __syncthreads();
    }
    if (t == 0) off[n] = carry_s;
}

__global__ void scatter_kernel(const int* __restrict__ ei, const int* __restrict__ off,
                               int* __restrict__ cur, int* __restrict__ csr,
                               int E, int Et) {
    int e = blockIdx.x * blockDim.x + threadIdx.x;
    if (e >= Et) return;
    int s, d;
    if (e < E) { s = ei[e]; d = ei[E + e]; } else { s = e - E; d = s; }
    int pos = off[d] + atomicAdd(&cur[d], 1);
    csr[pos] = s;
}

// ---------------------------------------------------------------------------
// Fused weight transpose+cvt: 3 jobs in one launch, 32x32 tiles.
// ---------------------------------------------------------------------------
__global__ void prep_t_kernel(const float* __restrict__ wa, __hip_bfloat16* __restrict__ wta,
                              const float* __restrict__ wb, __hip_bfloat16* __restrict__ wtb,
                              const float* __restrict__ wc, __hip_bfloat16* __restrict__ wtc,
                              int t0, int t1, int t2) {
    __shared__ float tile[32][33];
    int bid = blockIdx.x;
    const float* w; __hip_bfloat16* wt; int K, N, r;
    if (bid < t0)      { w = wa; wt = wta; K = 512;  N = 2048; r = bid; }
    else if (bid < t1) { w = wb; wt = wtb; K = 2048; N = 2048; r = bid - t0; }
    else               { w = wc; wt = wtc; K = 2048; N = 1024; r = bid - t1; }
    (void)t2;
    int kt = K >> 5;
    int kb = (r % kt) * 32, nb = (r / kt) * 32;
    int tx = threadIdx.x & 31, ty = threadIdx.x >> 5;
    for (int i = ty; i < 32; i += 8)
        tile[i][tx] = w[(size_t)(kb + i) * N + nb + tx];
    __syncthreads();
    for (int i = ty; i < 32; i += 8)
        wt[(size_t)(nb + i) * K + kb + tx] = __float2bfloat16(tile[tx][i]);
}

// Fused fp32->bf16 convert of proj_w then x (both sizes %4 == 0).
__global__ void cvt2_kernel(const float* __restrict__ a, __hip_bfloat16* __restrict__ ao,
                            int na4,
                            const float* __restrict__ b, __hip_bfloat16* __restrict__ bo,
                            int nb4) {
    int i = blockIdx.x * blockDim.x + threadIdx.x;
    const float* src; __hip_bfloat16* dst; int idx;
    if (i < na4) { src = a; dst = ao; idx = i * 4; }
    else if (i < na4 + nb4) { src = b; dst = bo; idx = (i - na4) * 4; }
    else return;
    float4 v = *(const float4*)(src + idx);
    dst[idx + 0] = __float2bfloat16(v.x);
    dst[idx + 1] = __float2bfloat16(v.y);
    dst[idx + 2] = __float2bfloat16(v.z);
    dst[idx + 3] = __float2bfloat16(v.w);
}

// b_eff[j] += partial over k-chunk of proj_b[k]*w1[k][j] (k-split, unrolled).
__global__ void beff_kernel(const float* __restrict__ pb, const float* __restrict__ w1,
                            float* __restrict__ beff, int N) {
    int j  = blockIdx.x * 256 + threadIdx.x;
    int k0 = blockIdx.y * 64;
    float s = 0.f;
#pragma unroll
    for (int k = 0; k < 64; k++)
        s = fmaf(pb[k0 + k], w1[(size_t)(k0 + k) * N + j], s);
    atomicAdd(&beff[j], s);
}

// ---------------------------------------------------------------------------
// bf16 MFMA GEMM: Cb[M,N] = bf16(A[M,K] @ BT[N,K]^T (+bias))
// 128x128 tile, BK=32, 256 threads (4 waves), 16x16x32 MFMA.
// XCD-aware 1-D swizzle (xcd = bid&7 owns contiguous x-stripe).
// NOTE (R7 post-mortem): do NOT fuse per-row reductions w/ atomics into this
// epilogue — 640k cross-XCD atomicAdds onto 80 KB serialized the pipe (+36%).
// ---------------------------------------------------------------------------
__device__ __forceinline__ void gload16(void* lds, const void* g) {
    __builtin_amdgcn_global_load_lds(
        (const __attribute__((address_space(1))) void*)g,
        (__attribute__((address_space(3))) void*)lds, 16, 0, 0);
}

__global__ __launch_bounds__(256) void gemm_bf16_kernel(
    const __hip_bfloat16* __restrict__ A,
    const __hip_bfloat16* __restrict__ BT,
    const float* __restrict__ bias,
    __hip_bfloat16* __restrict__ Cb,
    int M, int N, int K, int MB, int NB, int XT)
{
    __shared__ __align__(16) __hip_bfloat16 As[128 * 32];
    __shared__ __align__(16) __hip_bfloat16 Bs[128 * 32];

    const int bid  = blockIdx.x;
    const int xcd  = bid & 7;
    const int slot = bid >> 3;
    const int x_sub = slot / NB;
    const int yb    = slot - x_sub * NB;
    const int xb    = xcd * XT + x_sub;
    if (xb >= MB) return;

    const int tid = threadIdx.x;
    const int m0 = xb * 128, n0 = yb * 128;
    const int w = tid >> 6, l = tid & 63;
    const int wm = (w & 1) * 64, wn = (w >> 1) * 64;
    const int lm = l & 15, lq = l >> 4;

    f32x4 acc[4][4] = {};

    const int arow = tid >> 2;
    const int acol = (tid & 3) * 8;
    const __hip_bfloat16* Ag = A  + (size_t)(m0 + arow) * K + acol;
    const __hip_bfloat16* Bg = BT + (size_t)(n0 + arow) * K + acol;
    char* AsW = (char*)As + (w << 10);
    char* BsW = (char*)Bs + (w << 10);

    for (int k0 = 0; k0 < K; k0 += 32) {
        gload16(AsW,        Ag + k0);
        gload16(AsW + 4096, Ag + (size_t)64 * K + k0);
        gload16(BsW,        Bg + k0);
        gload16(BsW + 4096, Bg + (size_t)64 * K + k0);
        __syncthreads();
        bf16x8 af[4], bfr[4];
#pragma unroll
        for (int i = 0; i < 4; i++)
            af[i] = *(const bf16x8*)(As + (wm + i * 16 + lm) * 32 + lq * 8);
#pragma unroll
        for (int j = 0; j < 4; j++)
            bfr[j] = *(const bf16x8*)(Bs + (wn + j * 16 + lm) * 32 + lq * 8);
#pragma unroll
        for (int i = 0; i < 4; i++)
#pragma unroll
            for (int j = 0; j < 4; j++)
                acc[i][j] = __builtin_amdgcn_mfma_f32_16x16x32_bf16(
                    af[i], bfr[j], acc[i][j], 0, 0, 0);
        __syncthreads();
    }

#pragma unroll
    for (int i = 0; i < 4; i++) {
        int rb = m0 + wm + i * 16 + lq * 4;
#pragma unroll
        for (int r = 0; r < 4; r++) {
            int row = rb + r;
            if (row >= M) continue;
#pragma unroll
            for (int j = 0; j < 4; j++) {
                int col = n0 + wn + j * 16 + lm;
                float v = acc[i][j][r];
                if (bias) v += bias[col];
                Cb[(size_t)row * N + col] = __float2bfloat16(v);
            }
        }
    }
}

// ---------------------------------------------------------------------------
// es/ed: per-node per-head dot with a_src/a_dst (h in bf16). One wave/head.
// ---------------------------------------------------------------------------
__global__ void esed_kernel(const __hip_bfloat16* __restrict__ h,
                            const float* __restrict__ a_src,
                            const float* __restrict__ a_dst,
                            float* __restrict__ es, float* __restrict__ ed, int H) {
    int nidx = blockIdx.x;
    int t = threadIdx.x;
    int head = t >> 6, lane = t & 63;
    const unsigned short* hp =
        (const unsigned short*)h + (size_t)nidx * H * 512 + head * 512 + lane * 8;
    const float* sp = a_src + head * 512 + lane * 8;
    const float* dp = a_dst + head * 512 + lane * 8;
    u16x8 hv = *(const u16x8*)hp;
    float4 s0 = *(const float4*)sp, s1 = *(const float4*)(sp + 4);
    float4 d0 = *(const float4*)dp, d1 = *(const float4*)(dp + 4);
    float hf[8];
#pragma unroll
    for (int k = 0; k < 8; k++) hf[k] = bf2f(hv[k]);
    float s = hf[0]*s0.x + hf[1]*s0.y + hf[2]*s0.z + hf[3]*s0.w
            + hf[4]*s1.x + hf[5]*s1.y + hf[6]*s1.z + hf[7]*s1.w;
    float d = hf[0]*d0.x + hf[1]*d0.y + hf[2]*d0.z + hf[3]*d0.w
            + hf[4]*d1.x + hf[5]*d1.y + hf[6]*d1.z + hf[7]*d1.w;
    for (int o = 32; o; o >>= 1) { s += __shfl_down(s, o); d += __shfl_down(d, o); }
    if (lane == 0) { es[nidx * H + head] = s; ed[nidx * H + head] = d; }
}

// ---------------------------------------------------------------------------
// Aggregation: ONE block per dst, all heads. Thread t owns channels
// [t*VEC, t*VEC+VEC). 4x edge unroll. MEAN variant fuses head-mean + bias.
// ---------------------------------------------------------------------------
template<int H, int VEC, bool MEAN>
__global__ __launch_bounds__(256) void agg_kernel(
    const __hip_bfloat16* __restrict__ h, const float* __restrict__ es,
    const float* __restrict__ ed, const int* __restrict__ csr,
    const int* __restrict__ off, const float* __restrict__ bias,
    float* __restrict__ outF, __hip_bfloat16* __restrict__ outB, int do_elu)
{
    constexpr int HS = H * 512;
    __shared__ float red[MEAN ? 1024 : 1];
    int d = blockIdx.x, t = threadIdx.x;
    int c0 = t * VEC;
    int head = c0 >> 9;
    float edd = ed[d * H + head];
    int beg = off[d], end = off[d + 1];
    float acc[VEC];
#pragma unroll
    for (int k = 0; k < VEC; k++) acc[k] = 0.f;
    float den = 0.f;
    const unsigned short* hb = (const unsigned short*)h;

    int i = beg;
    for (; i + 3 < end; i += 4) {
        int   s[4];
        float wgt[4];
#pragma unroll
        for (int u = 0; u < 4; u++) {
            s[u] = csr[i + u];
            float e = es[s[u] * H + head] + edd;
            e = (e > 0.f) ? e : 0.2f * e;
            wgt[u] = __expf(e);
        }
        if constexpr (VEC == 8) {
            u16x8 v[4];
#pragma unroll
            for (int u = 0; u < 4; u++)
                v[u] = *(const u16x8*)(hb + (size_t)s[u] * HS + c0);
#pragma unroll
            for (int u = 0; u < 4; u++) {
                den += wgt[u];
#pragma unroll
                for (int k = 0; k < 8; k++) acc[k] = fmaf(wgt[u], bf2f(v[u][k]), acc[k]);
            }
        } else {
            u16x4 v[4];
#pragma unroll
            for (int u = 0; u < 4; u++)
                v[u] = *(const u16x4*)(hb + (size_t)s[u] * HS + c0);
#pragma unroll
            for (int u = 0; u < 4; u++) {
                den += wgt[u];
#pragma unroll
                for (int k = 0; k < VEC; k++) acc[k] = fmaf(wgt[u], bf2f(v[u][k]), acc[k]);
            }
        }
    }
    for (; i < end; i++) {
        int s0 = csr[i];
        float e0 = es[s0 * H + head] + edd;
        e0 = (e0 > 0.f) ? e0 : 0.2f * e0;
        float w0 = __expf(e0);
        den += w0;
        const unsigned short* hp0 = hb + (size_t)s0 * HS + c0;
        if constexpr (VEC == 8) {
            u16x8 v0 = *(const u16x8*)hp0;
#pragma unroll
            for (int k = 0; k < 8; k++) acc[k] = fmaf(w0, bf2f(v0[k]), acc[k]);
        } else {
            u16x4 v0 = *(const u16x4*)hp0;
#pragma unroll
            for (int k = 0; k < VEC; k++) acc[k] = fmaf(w0, bf2f(v0[k]), acc[k]);
        }
    }

    float inv = 1.f / den;
    if constexpr (!MEAN) {
        u16x8 ov;
#pragma unroll
        for (int k = 0; k < VEC; k++) {
            float v = acc[k] * inv + bias[c0 + k];
            if (do_elu) v = (v > 0.f) ? v : expm1f(v);
            ov[k] = f2bf(v);
        }
        *(u16x8*)((unsigned short*)outB + (size_t)d * HS + c0) = ov;
    } else {
#pragma unroll
        for (int k = 0; k < VEC; k++) red[c0 + k] = acc[k] * inv;
        __syncthreads();
        if (t < 128) {
#pragma unroll
            for (int k = 0; k < 4; k++) {
                int c = t * 4 + k;
                outF[(size_t)d * 512 + c] = 0.5f * (red[c] + red[c + 512]) + bias[c];
            }
        }
    }
}

// ---------------------------------------------------------------------------
extern "C" void kernel_launch(void* const* d_in, const int* in_sizes, int n_in,
                              void* d_out, int out_size, void* d_ws, size_t ws_size,
                              hipStream_t stream) {
    const float* x      = (const float*)d_in[0];
    const int*   ei     = (const int*)  d_in[1];
    const float* proj_w = (const float*)d_in[2];
    const float* proj_b = (const float*)d_in[3];
    const float* w1  = (const float*)d_in[4];
    const float* as1 = (const float*)d_in[5];
    const float* ad1 = (const float*)d_in[6];
    const float* b1  = (const float*)d_in[7];
    const float* w2  = (const float*)d_in[8];
    const float* as2 = (const float*)d_in[9];
    const float* ad2 = (const float*)d_in[10];
    const float* b2  = (const float*)d_in[11];
    const float* w3  = (const float*)d_in[12];
    const float* as3 = (const float*)d_in[13];
    const float* ad3 = (const float*)d_in[14];
    const float* b3  = (const float*)d_in[15];

    const int n    = in_sizes[0] / 256;   // 10000
    const int E    = in_sizes[1] / 2;     // 160000
    const int Et   = E + n;               // 170000
    const int MB   = CDIV(n, 128);        // 79
    const int Mpad = MB * 128;            // 10112
    const int XT   = CDIV(MB, 8);         // 10

    char* p = (char*)d_ws;
    auto carve = [&](size_t bytes) {
        void* r = (void*)p;
        p += (bytes + 255) & ~(size_t)255;
        return r;
    };
    __hip_bfloat16* h_bf    = (__hip_bfloat16*)carve((size_t)Mpad * 2048 * sizeof(__hip_bfloat16));
    __hip_bfloat16* act_bf  = (__hip_bfloat16*)carve((size_t)Mpad * 2048 * sizeof(__hip_bfloat16));
    __hip_bfloat16* x_bf    = (__hip_bfloat16*)carve((size_t)Mpad * 256 * sizeof(__hip_bfloat16));
    __hip_bfloat16* pw_bf   = (__hip_bfloat16*)carve((size_t)256 * 512 * sizeof(__hip_bfloat16));
    __hip_bfloat16* w1t     = (__hip_bfloat16*)carve((size_t)2048 * 512 * sizeof(__hip_bfloat16));
    __hip_bfloat16* w2t     = (__hip_bfloat16*)carve((size_t)2048 * 2048 * sizeof(__hip_bfloat16));
    __hip_bfloat16* w3t     = (__hip_bfloat16*)carve((size_t)1024 * 2048 * sizeof(__hip_bfloat16));
    __hip_bfloat16* w_efft  = (__hip_bfloat16*)carve((size_t)2048 * 256 * sizeof(__hip_bfloat16));
    float* b_eff = (float*)carve((size_t)2048 * sizeof(float));
    float* es  = (float*)carve((size_t)n * 4 * sizeof(float));
    float* ed  = (float*)carve((size_t)n * 4 * sizeof(float));
    int* deg = (int*)carve((size_t)2 * n * sizeof(int));   // deg + cur contiguous
    int* cur = deg + n;
    int* off = (int*)carve((size_t)(n + 1) * sizeof(int));
    int* csr = (int*)carve((size_t)Et * sizeof(int));
    (void)ws_size; (void)n_in;

    // --- CSR build ---
    hipMemsetAsync(deg, 0, 2 * n * sizeof(int), stream);
    hipMemsetAsync(b_eff, 0, 2048 * sizeof(float), stream);
    hist_kernel<<<CDIV(Et, 256), 256, 0, stream>>>(ei, deg, E, Et);
    scan_kernel<<<1, 1024, 0, stream>>>(deg, off, n);
    scatter_kernel<<<CDIV(Et, 256), 256, 0, stream>>>(ei, off, cur, csr, E, Et);

    // --- weight prep (fused) ---
    const int t0 = (512 / 32) * (2048 / 32);            // 1024
    const int t1 = t0 + (2048 / 32) * (2048 / 32);      // +4096
    const int t2 = t1 + (2048 / 32) * (1024 / 32);      // +2048
    prep_t_kernel<<<t2, 256, 0, stream>>>(w1, w1t, w2, w2t, w3, w3t, t0, t1, t2);
    const int na4 = 256 * 512 / 4, nb4 = n * 256 / 4;
    cvt2_kernel<<<CDIV(na4 + nb4, 256), 256, 0, stream>>>(proj_w, pw_bf, na4, x, x_bf, nb4);

    // --- fold proj into layer 1 ---
    gemm_bf16_kernel<<<8 * 2 * 2, 256, 0, stream>>>(
        w1t, pw_bf, nullptr, w_efft, 2048, 256, 512, 16, 2, 2);
    beff_kernel<<<dim3(2048 / 256, 512 / 64), 256, 0, stream>>>(proj_b, w1, b_eff, 2048);

    auto gemm_grid = [&](int NB) { return 8 * XT * NB; };

    // --- layer 1 (H=4, concat, ELU):  h = x @ W_eff + b_eff ---
    gemm_bf16_kernel<<<gemm_grid(16), 256, 0, stream>>>(
        x_bf, w_efft, b_eff, h_bf, n, 2048, 256, MB, 16, XT);
    esed_kernel<<<n, 4 * 64, 0, stream>>>(h_bf, as1, ad1, es, ed, 4);
    agg_kernel<4, 8, false><<<n, 256, 0, stream>>>(h_bf, es, ed, csr, off, b1,
                                                   nullptr, act_bf, 1);

    // --- layer 2 (H=4, concat, ELU) ---
    gemm_bf16_kernel<<<gemm_grid(16), 256, 0, stream>>>(
        act_bf, w2t, nullptr, h_bf, n, 2048, 2048, MB, 16, XT);
    esed_kernel<<<n, 4 * 64, 0, stream>>>(h_bf, as2, ad2, es, ed, 4);
    agg_kernel<4, 8, false><<<n, 256, 0, stream>>>(h_bf, es, ed, csr, off, b2,
                                                   nullptr, act_bf, 1);

    // --- layer 3 (H=2, mean+bias fused, no ELU) ---
    gemm_bf16_kernel<<<gemm_grid(8), 256, 0, stream>>>(
        act_bf, w3t, nullptr, h_bf, n, 1024, 2048, MB, 8, XT);
    esed_kernel<<<n, 2 * 64, 0, stream>>>(h_bf, as3, ad3, es, ed, 2);
    agg_kernel<2, 4, true><<<n, 256, 0, stream>>>(h_bf, es, ed, csr, off, b3,
                                                  (float*)d_out, nullptr, 0);
}

// Round 9
// 635.329 us; speedup vs baseline: 1.1708x; 1.0499x over previous
//
#include <hip/hip_runtime.h>
#include <hip/hip_bf16.h>
#include <math.h>

#define CDIV(a,b) (((a)+(b)-1)/(b))

typedef __bf16  bf16x8 __attribute__((ext_vector_type(8)));
typedef float   f32x4  __attribute__((ext_vector_type(4)));
typedef unsigned short u16x8 __attribute__((ext_vector_type(8)));
typedef unsigned short u16x4 __attribute__((ext_vector_type(4)));

__device__ __forceinline__ float bf2f(unsigned short u) {
    union { unsigned int i; float f; } x; x.i = ((unsigned int)u) << 16; return x.f;
}
__device__ __forceinline__ unsigned short f2bf(float f) {
    union { float f; unsigned int i; } x; x.f = f;
    unsigned int r = x.i + 0x7fff + ((x.i >> 16) & 1);   // RNE, finite inputs
    return (unsigned short)(r >> 16);
}

// ---------------------------------------------------------------------------
// CSR build (by destination node). Edges = [E graph edges] + [n self-loops].
// ---------------------------------------------------------------------------
__global__ void hist_kernel(const int* __restrict__ ei, int* __restrict__ deg,
                            int E, int Et) {
    int e = blockIdx.x * blockDim.x + threadIdx.x;
    if (e >= Et) return;
    int d = (e < E) ? ei[E + e] : (e - E);
    atomicAdd(&deg[d], 1);
}

// Single-block exclusive scan, wave-shuffle based.
__global__ void scan_kernel(const int* __restrict__ deg, int* __restrict__ off, int n) {
    __shared__ int wsum[16];
    __shared__ int carry_s;
    int t = threadIdx.x, lane = t & 63, wv = t >> 6;
    if (t == 0) carry_s = 0;
    __syncthreads();
    for (int base = 0; base < n; base += 1024) {
        int v = (base + t < n) ? deg[base + t] : 0;
        int x = v;
#pragma unroll
        for (int o = 1; o < 64; o <<= 1) {
            int y = __shfl_up(x, o);
            if (lane >= o) x += y;
        }
        if (lane == 63) wsum[wv] = x;
        __syncthreads();
        if (wv == 0 && lane < 16) {
            int s = wsum[lane];
#pragma unroll
            for (int o = 1; o < 16; o <<= 1) {
                int y = __shfl_up(s, o);
                if (lane >= o) s += y;
            }
            wsum[lane] = s;
        }
        __syncthreads();
        int wprev = (wv == 0) ? 0 : wsum[wv - 1];
        int incl = carry_s + wprev + x;
        if (base + t < n) off[base + t] = incl - v;
        __syncthreads();
        if (t == 1023) carry_s = incl;
        __syncthreads();
    }
    if (t == 0) off[n] = carry_s;
}

__global__ void scatter_kernel(const int* __restrict__ ei, const int* __restrict__ off,
                               int* __restrict__ cur, int* __restrict__ csr,
                               int E, int Et) {
    int e = blockIdx.x * blockDim.x + threadIdx.x;
    if (e >= Et) return;
    int s, d;
    if (e < E) { s = ei[e]; d = ei[E + e]; } else { s = e - E; d = s; }
    int pos = off[d] + atomicAdd(&cur[d], 1);
    csr[pos] = s;
}

// ---------------------------------------------------------------------------
// Fused weight transpose+cvt: 3 jobs in one launch, 32x32 tiles.
// ---------------------------------------------------------------------------
__global__ void prep_t_kernel(const float* __restrict__ wa, __hip_bfloat16* __restrict__ wta,
                              const float* __restrict__ wb, __hip_bfloat16* __restrict__ wtb,
                              const float* __restrict__ wc, __hip_bfloat16* __restrict__ wtc,
                              int t0, int t1, int t2) {
    __shared__ float tile[32][33];
    int bid = blockIdx.x;
    const float* w; __hip_bfloat16* wt; int K, N, r;
    if (bid < t0)      { w = wa; wt = wta; K = 512;  N = 2048; r = bid; }
    else if (bid < t1) { w = wb; wt = wtb; K = 2048; N = 2048; r = bid - t0; }
    else               { w = wc; wt = wtc; K = 2048; N = 1024; r = bid - t1; }
    (void)t2;
    int kt = K >> 5;
    int kb = (r % kt) * 32, nb = (r / kt) * 32;
    int tx = threadIdx.x & 31, ty = threadIdx.x >> 5;
    for (int i = ty; i < 32; i += 8)
        tile[i][tx] = w[(size_t)(kb + i) * N + nb + tx];
    __syncthreads();
    for (int i = ty; i < 32; i += 8)
        wt[(size_t)(nb + i) * K + kb + tx] = __float2bfloat16(tile[tx][i]);
}

// Fused fp32->bf16 convert of proj_w then x (both sizes %4 == 0).
__global__ void cvt2_kernel(const float* __restrict__ a, __hip_bfloat16* __restrict__ ao,
                            int na4,
                            const float* __restrict__ b, __hip_bfloat16* __restrict__ bo,
                            int nb4) {
    int i = blockIdx.x * blockDim.x + threadIdx.x;
    const float* src; __hip_bfloat16* dst; int idx;
    if (i < na4) { src = a; dst = ao; idx = i * 4; }
    else if (i < na4 + nb4) { src = b; dst = bo; idx = (i - na4) * 4; }
    else return;
    float4 v = *(const float4*)(src + idx);
    dst[idx + 0] = __float2bfloat16(v.x);
    dst[idx + 1] = __float2bfloat16(v.y);
    dst[idx + 2] = __float2bfloat16(v.z);
    dst[idx + 3] = __float2bfloat16(v.w);
}

// b_eff[j] += partial over k-chunk of proj_b[k]*w1[k][j] (k-split, unrolled).
__global__ void beff_kernel(const float* __restrict__ pb, const float* __restrict__ w1,
                            float* __restrict__ beff, int N) {
    int j  = blockIdx.x * 256 + threadIdx.x;
    int k0 = blockIdx.y * 64;
    float s = 0.f;
#pragma unroll
    for (int k = 0; k < 64; k++)
        s = fmaf(pb[k0 + k], w1[(size_t)(k0 + k) * N + j], s);
    atomicAdd(&beff[j], s);
}

// ---------------------------------------------------------------------------
// va[j][256] = W_eff[:, head-block j] @ a_vec   (j<4: a_src head j; j>=4: a_dst)
// cvec[j] = b_eff[head-block] . a_vec ;  block 8 computes b1s = b_eff + b1.
// ---------------------------------------------------------------------------
__global__ void va_kernel(const __hip_bfloat16* __restrict__ w_efft,
                          const float* __restrict__ b_eff,
                          const float* __restrict__ as1, const float* __restrict__ ad1,
                          const float* __restrict__ b1,
                          float* __restrict__ va, float* __restrict__ cvec,
                          float* __restrict__ b1s) {
    int j = blockIdx.x, t = threadIdx.x;
    if (j == 8) {
        for (int i = t; i < 2048; i += 256) b1s[i] = b_eff[i] + b1[i];
        return;
    }
    int h = j & 3;
    const float* a = ((j < 4) ? as1 : ad1) + h * 512;
    __shared__ float aLDS[512];
    __shared__ float red[256];
    for (int c = t; c < 512; c += 256) aLDS[c] = a[c];
    __syncthreads();
    float acc = 0.f;
    const unsigned short* wb = (const unsigned short*)w_efft + (size_t)h * 512 * 256 + t;
    for (int c = 0; c < 512; c++)
        acc = fmaf(aLDS[c], bf2f(wb[(size_t)c * 256]), acc);
    va[j * 256 + t] = acc;
    float cp = b_eff[h * 512 + t] * aLDS[t] + b_eff[h * 512 + 256 + t] * aLDS[256 + t];
    red[t] = cp;
    __syncthreads();
    for (int s = 128; s > 0; s >>= 1) {
        if (t < s) red[t] += red[t + s];
        __syncthreads();
    }
    if (t == 0) cvec[j] = red[0];
}

// ---------------------------------------------------------------------------
// es1/ed1: es[node][h] = x_bf[node] . va[h] + cvec[h]  (one wave per node).
// ---------------------------------------------------------------------------
__global__ void es1_kernel(const __hip_bfloat16* __restrict__ x_bf,
                           const float* __restrict__ va, const float* __restrict__ cvec,
                           float* __restrict__ es, float* __restrict__ ed) {
    int node = blockIdx.x, l = threadIdx.x;
    u16x4 xv = *(const u16x4*)((const unsigned short*)x_bf + (size_t)node * 256 + l * 4);
    float xf[4];
#pragma unroll
    for (int k = 0; k < 4; k++) xf[k] = bf2f(xv[k]);
    float dot[8];
#pragma unroll
    for (int j = 0; j < 8; j++) {
        float4 v = *(const float4*)(va + j * 256 + l * 4);
        dot[j] = xf[0] * v.x + xf[1] * v.y + xf[2] * v.z + xf[3] * v.w;
    }
#pragma unroll
    for (int j = 0; j < 8; j++)
        for (int o = 32; o; o >>= 1) dot[j] += __shfl_down(dot[j], o);
    if (l == 0) {
#pragma unroll
        for (int h = 0; h < 4; h++) {
            es[node * 4 + h] = dot[h] + cvec[h];
            ed[node * 4 + h] = dot[4 + h] + cvec[4 + h];
        }
    }
}

// ---------------------------------------------------------------------------
// Layer-1 aggregation in INPUT space (256 ch): one block per dst.
// Phase A (per 64-edge chunk): threads (i,h) compute alpha into LDS.
// Phase B: thread t owns channel t, accumulates 4 head-sums of x_src[t].
// z[d][h*256+t] = bf16(acc_h / den_h).
// ---------------------------------------------------------------------------
__global__ __launch_bounds__(256) void agg1x_kernel(
    const __hip_bfloat16* __restrict__ x_bf, const float* __restrict__ es,
    const float* __restrict__ ed, const int* __restrict__ csr,
    const int* __restrict__ off, __hip_bfloat16* __restrict__ z)
{
    __shared__ float alds[64][4];
    __shared__ int   slds[64];
    int d = blockIdx.x, t = threadIdx.x;
    int beg = off[d], end = off[d + 1];
    float acc[4] = {0.f, 0.f, 0.f, 0.f}, den[4] = {0.f, 0.f, 0.f, 0.f};
    float edd[4];
#pragma unroll
    for (int h = 0; h < 4; h++) edd[h] = ed[d * 4 + h];
    const unsigned short* xb = (const unsigned short*)x_bf;

    for (int cb = beg; cb < end; cb += 64) {
        int cl = end - cb; if (cl > 64) cl = 64;
        int i = t >> 2, h = t & 3;
        if (i < cl) {
            int s = csr[cb + i];
            if (h == 0) slds[i] = s;
            float e = es[s * 4 + h] + edd[h];
            e = (e > 0.f) ? e : 0.2f * e;
            alds[i][h] = __expf(e);
        }
        __syncthreads();
        for (int ii = 0; ii < cl; ii++) {
            int s = slds[ii];
            float xv = bf2f(xb[(size_t)s * 256 + t]);
#pragma unroll
            for (int hh = 0; hh < 4; hh++) {
                float a = alds[ii][hh];
                den[hh] += a;
                acc[hh] = fmaf(a, xv, acc[hh]);
            }
        }
        __syncthreads();
    }
    unsigned short* zb = (unsigned short*)z + (size_t)d * 1024;
#pragma unroll
    for (int h = 0; h < 4; h++)
        zb[h * 256 + t] = f2bf(acc[h] / den[h]);
}

// ---------------------------------------------------------------------------
// bf16 MFMA GEMM: Cb[M,N] = bf16(act( A[M,K(lda)] @ BT[N,K]^T + bias ))
// 128x128 tile, BK=32, 256 threads (4 waves), 16x16x32 MFMA.
// lda = A row stride; hko != 0 -> A col base += (n0>>9)*hko (per-head K-block
// for the layer-1 post-aggregation GEMM). do_elu: ELU in epilogue.
// XCD-aware 1-D swizzle (xcd = bid&7 owns contiguous x-stripe).
// NOTE (R7): never fuse cross-XCD atomic reductions into this epilogue.
// ---------------------------------------------------------------------------
__device__ __forceinline__ void gload16(void* lds, const void* g) {
    __builtin_amdgcn_global_load_lds(
        (const __attribute__((address_space(1))) void*)g,
        (__attribute__((address_space(3))) void*)lds, 16, 0, 0);
}

__global__ __launch_bounds__(256) void gemm_bf16_kernel(
    const __hip_bfloat16* __restrict__ A,
    const __hip_bfloat16* __restrict__ BT,
    const float* __restrict__ bias,
    __hip_bfloat16* __restrict__ Cb,
    int M, int N, int K, int lda, int hko, int do_elu,
    int MB, int NB, int XT)
{
    __shared__ __align__(16) __hip_bfloat16 As[128 * 32];
    __shared__ __align__(16) __hip_bfloat16 Bs[128 * 32];

    const int bid  = blockIdx.x;
    const int xcd  = bid & 7;
    const int slot = bid >> 3;
    const int x_sub = slot / NB;
    const int yb    = slot - x_sub * NB;
    const int xb    = xcd * XT + x_sub;
    if (xb >= MB) return;

    const int tid = threadIdx.x;
    const int m0 = xb * 128, n0 = yb * 128;
    const int w = tid >> 6, l = tid & 63;
    const int wm = (w & 1) * 64, wn = (w >> 1) * 64;
    const int lm = l & 15, lq = l >> 4;

    f32x4 acc[4][4] = {};

    const int arow = tid >> 2;
    const int acol = (tid & 3) * 8;
    const __hip_bfloat16* Ag = A + (size_t)(m0 + arow) * lda + acol + (n0 >> 9) * hko;
    const __hip_bfloat16* Bg = BT + (size_t)(n0 + arow) * K + acol;
    char* AsW = (char*)As + (w << 10);
    char* BsW = (char*)Bs + (w << 10);

    for (int k0 = 0; k0 < K; k0 += 32) {
        gload16(AsW,        Ag + k0);
        gload16(AsW + 4096, Ag + (size_t)64 * lda + k0);
        gload16(BsW,        Bg + k0);
        gload16(BsW + 4096, Bg + (size_t)64 * K + k0);
        __syncthreads();
        bf16x8 af[4], bfr[4];
#pragma unroll
        for (int i = 0; i < 4; i++)
            af[i] = *(const bf16x8*)(As + (wm + i * 16 + lm) * 32 + lq * 8);
#pragma unroll
        for (int j = 0; j < 4; j++)
            bfr[j] = *(const bf16x8*)(Bs + (wn + j * 16 + lm) * 32 + lq * 8);
#pragma unroll
        for (int i = 0; i < 4; i++)
#pragma unroll
            for (int j = 0; j < 4; j++)
                acc[i][j] = __builtin_amdgcn_mfma_f32_16x16x32_bf16(
                    af[i], bfr[j], acc[i][j], 0, 0, 0);
        __syncthreads();
    }

#pragma unroll
    for (int i = 0; i < 4; i++) {
        int rb = m0 + wm + i * 16 + lq * 4;
#pragma unroll
        for (int r = 0; r < 4; r++) {
            int row = rb + r;
            if (row >= M) continue;
#pragma unroll
            for (int j = 0; j < 4; j++) {
                int col = n0 + wn + j * 16 + lm;
                float v = acc[i][j][r];
                if (bias) v += bias[col];
                if (do_elu) v = (v > 0.f) ? v : expm1f(v);
                Cb[(size_t)row * N + col] = __float2bfloat16(v);
            }
        }
    }
}

// ---------------------------------------------------------------------------
// es/ed: per-node per-head dot with a_src/a_dst (h in bf16). One wave/head.
// ---------------------------------------------------------------------------
__global__ void esed_kernel(const __hip_bfloat16* __restrict__ h,
                            const float* __restrict__ a_src,
                            const float* __restrict__ a_dst,
                            float* __restrict__ es, float* __restrict__ ed, int H) {
    int nidx = blockIdx.x;
    int t = threadIdx.x;
    int head = t >> 6, lane = t & 63;
    const unsigned short* hp =
        (const unsigned short*)h + (size_t)nidx * H * 512 + head * 512 + lane * 8;
    const float* sp = a_src + head * 512 + lane * 8;
    const float* dp = a_dst + head * 512 + lane * 8;
    u16x8 hv = *(const u16x8*)hp;
    float4 s0 = *(const float4*)sp, s1 = *(const float4*)(sp + 4);
    float4 d0 = *(const float4*)dp, d1 = *(const float4*)(dp + 4);
    float hf[8];
#pragma unroll
    for (int k = 0; k < 8; k++) hf[k] = bf2f(hv[k]);
    float s = hf[0]*s0.x + hf[1]*s0.y + hf[2]*s0.z + hf[3]*s0.w
            + hf[4]*s1.x + hf[5]*s1.y + hf[6]*s1.z + hf[7]*s1.w;
    float d = hf[0]*d0.x + hf[1]*d0.y + hf[2]*d0.z + hf[3]*d0.w
            + hf[4]*d1.x + hf[5]*d1.y + hf[6]*d1.z + hf[7]*d1.w;
    for (int o = 32; o; o >>= 1) { s += __shfl_down(s, o); d += __shfl_down(d, o); }
    if (lane == 0) { es[nidx * H + head] = s; ed[nidx * H + head] = d; }
}

// ---------------------------------------------------------------------------
// Aggregation (layers 2/3): ONE block per dst, all heads. Thread t owns
// channels [t*VEC, t*VEC+VEC). 4x edge unroll. MEAN variant fuses mean+bias.
// ---------------------------------------------------------------------------
template<int H, int VEC, bool MEAN>
__global__ __launch_bounds__(256) void agg_kernel(
    const __hip_bfloat16* __restrict__ h, const float* __restrict__ es,
    const float* __restrict__ ed, const int* __restrict__ csr,
    const int* __restrict__ off, const float* __restrict__ bias,
    float* __restrict__ outF, __hip_bfloat16* __restrict__ outB, int do_elu)
{
    constexpr int HS = H * 512;
    __shared__ float red[MEAN ? 1024 : 1];
    int d = blockIdx.x, t = threadIdx.x;
    int c0 = t * VEC;
    int head = c0 >> 9;
    float edd = ed[d * H + head];
    int beg = off[d], end = off[d + 1];
    float acc[VEC];
#pragma unroll
    for (int k = 0; k < VEC; k++) acc[k] = 0.f;
    float den = 0.f;
    const unsigned short* hb = (const unsigned short*)h;

    int i = beg;
    for (; i + 3 < end; i += 4) {
        int   s[4];
        float wgt[4];
#pragma unroll
        for (int u = 0; u < 4; u++) {
            s[u] = csr[i + u];
            float e = es[s[u] * H + head] + edd;
            e = (e > 0.f) ? e : 0.2f * e;
            wgt[u] = __expf(e);
        }
        if constexpr (VEC == 8) {
            u16x8 v[4];
#pragma unroll
            for (int u = 0; u < 4; u++)
                v[u] = *(const u16x8*)(hb + (size_t)s[u] * HS + c0);
#pragma unroll
            for (int u = 0; u < 4; u++) {
                den += wgt[u];
#pragma unroll
                for (int k = 0; k < 8; k++) acc[k] = fmaf(wgt[u], bf2f(v[u][k]), acc[k]);
            }
        } else {
            u16x4 v[4];
#pragma unroll
            for (int u = 0; u < 4; u++)
                v[u] = *(const u16x4*)(hb + (size_t)s[u] * HS + c0);
#pragma unroll
            for (int u = 0; u < 4; u++) {
                den += wgt[u];
#pragma unroll
                for (int k = 0; k < VEC; k++) acc[k] = fmaf(wgt[u], bf2f(v[u][k]), acc[k]);
            }
        }
    }
    for (; i < end; i++) {
        int s0 = csr[i];
        float e0 = es[s0 * H + head] + edd;
        e0 = (e0 > 0.f) ? e0 : 0.2f * e0;
        float w0 = __expf(e0);
        den += w0;
        const unsigned short* hp0 = hb + (size_t)s0 * HS + c0;
        if constexpr (VEC == 8) {
            u16x8 v0 = *(const u16x8*)hp0;
#pragma unroll
            for (int k = 0; k < 8; k++) acc[k] = fmaf(w0, bf2f(v0[k]), acc[k]);
        } else {
            u16x4 v0 = *(const u16x4*)hp0;
#pragma unroll
            for (int k = 0; k < VEC; k++) acc[k] = fmaf(w0, bf2f(v0[k]), acc[k]);
        }
    }

    float inv = 1.f / den;
    if constexpr (!MEAN) {
        u16x8 ov;
#pragma unroll
        for (int k = 0; k < VEC; k++) {
            float v = acc[k] * inv + bias[c0 + k];
            if (do_elu) v = (v > 0.f) ? v : expm1f(v);
            ov[k] = f2bf(v);
        }
        *(u16x8*)((unsigned short*)outB + (size_t)d * HS + c0) = ov;
    } else {
#pragma unroll
        for (int k = 0; k < VEC; k++) red[c0 + k] = acc[k] * inv;
        __syncthreads();
        if (t < 128) {
#pragma unroll
            for (int k = 0; k < 4; k++) {
                int c = t * 4 + k;
                outF[(size_t)d * 512 + c] = 0.5f * (red[c] + red[c + 512]) + bias[c];
            }
        }
    }
}

// ---------------------------------------------------------------------------
extern "C" void kernel_launch(void* const* d_in, const int* in_sizes, int n_in,
                              void* d_out, int out_size, void* d_ws, size_t ws_size,
                              hipStream_t stream) {
    const float* x      = (const float*)d_in[0];
    const int*   ei     = (const int*)  d_in[1];
    const float* proj_w = (const float*)d_in[2];
    const float* proj_b = (const float*)d_in[3];
    const float* w1  = (const float*)d_in[4];
    const float* as1 = (const float*)d_in[5];
    const float* ad1 = (const float*)d_in[6];
    const float* b1  = (const float*)d_in[7];
    const float* w2  = (const float*)d_in[8];
    const float* as2 = (const float*)d_in[9];
    const float* ad2 = (const float*)d_in[10];
    const float* b2  = (const float*)d_in[11];
    const float* w3  = (const float*)d_in[12];
    const float* as3 = (const float*)d_in[13];
    const float* ad3 = (const float*)d_in[14];
    const float* b3  = (const float*)d_in[15];

    const int n    = in_sizes[0] / 256;   // 10000
    const int E    = in_sizes[1] / 2;     // 160000
    const int Et   = E + n;               // 170000
    const int MB   = CDIV(n, 128);        // 79
    const int Mpad = MB * 128;            // 10112
    const int XT   = CDIV(MB, 8);         // 10

    char* p = (char*)d_ws;
    auto carve = [&](size_t bytes) {
        void* r = (void*)p;
        p += (bytes + 255) & ~(size_t)255;
        return r;
    };
    __hip_bfloat16* h_bf    = (__hip_bfloat16*)carve((size_t)Mpad * 2048 * sizeof(__hip_bfloat16));
    __hip_bfloat16* act_bf  = (__hip_bfloat16*)carve((size_t)Mpad * 2048 * sizeof(__hip_bfloat16));
    __hip_bfloat16* x_bf    = (__hip_bfloat16*)carve((size_t)Mpad * 256 * sizeof(__hip_bfloat16));
    __hip_bfloat16* pw_bf   = (__hip_bfloat16*)carve((size_t)256 * 512 * sizeof(__hip_bfloat16));
    __hip_bfloat16* w1t     = (__hip_bfloat16*)carve((size_t)2048 * 512 * sizeof(__hip_bfloat16));
    __hip_bfloat16* w2t     = (__hip_bfloat16*)carve((size_t)2048 * 2048 * sizeof(__hip_bfloat16));
    __hip_bfloat16* w3t     = (__hip_bfloat16*)carve((size_t)1024 * 2048 * sizeof(__hip_bfloat16));
    __hip_bfloat16* w_efft  = (__hip_bfloat16*)carve((size_t)2048 * 256 * sizeof(__hip_bfloat16));
    float* b_eff = (float*)carve((size_t)2048 * sizeof(float));
    float* b1s   = (float*)carve((size_t)2048 * sizeof(float));
    float* va    = (float*)carve((size_t)8 * 256 * sizeof(float));
    float* cvec  = (float*)carve((size_t)8 * sizeof(float));
    float* es  = (float*)carve((size_t)n * 4 * sizeof(float));
    float* ed  = (float*)carve((size_t)n * 4 * sizeof(float));
    int* deg = (int*)carve((size_t)2 * n * sizeof(int));   // deg + cur contiguous
    int* cur = deg + n;
    int* off = (int*)carve((size_t)(n + 1) * sizeof(int));
    int* csr = (int*)carve((size_t)Et * sizeof(int));
    __hip_bfloat16* z_bf = h_bf;   // layer-1 aggregated-x [Mpad,1024], overlays h_bf
    (void)ws_size; (void)n_in;

    // --- CSR build ---
    hipMemsetAsync(deg, 0, 2 * n * sizeof(int), stream);
    hipMemsetAsync(b_eff, 0, 2048 * sizeof(float), stream);
    hist_kernel<<<CDIV(Et, 256), 256, 0, stream>>>(ei, deg, E, Et);
    scan_kernel<<<1, 1024, 0, stream>>>(deg, off, n);
    scatter_kernel<<<CDIV(Et, 256), 256, 0, stream>>>(ei, off, cur, csr, E, Et);

    // --- weight prep (fused) ---
    const int t0 = (512 / 32) * (2048 / 32);            // 1024
    const int t1 = t0 + (2048 / 32) * (2048 / 32);      // +4096
    const int t2 = t1 + (2048 / 32) * (1024 / 32);      // +2048
    prep_t_kernel<<<t2, 256, 0, stream>>>(w1, w1t, w2, w2t, w3, w3t, t0, t1, t2);
    const int na4 = 256 * 512 / 4, nb4 = n * 256 / 4;
    cvt2_kernel<<<CDIV(na4 + nb4, 256), 256, 0, stream>>>(proj_w, pw_bf, na4, x, x_bf, nb4);

    // --- fold proj into layer 1: W_eff^T[2048,256]; b_eff = proj_b @ w1 ---
    gemm_bf16_kernel<<<8 * 2 * 2, 256, 0, stream>>>(
        w1t, pw_bf, nullptr, w_efft, 2048, 256, 512, 512, 0, 0, 16, 2, 2);
    beff_kernel<<<dim3(2048 / 256, 512 / 64), 256, 0, stream>>>(proj_b, w1, b_eff, 2048);

    // --- layer-1 attention vectors + constants; b1s = b_eff + b1 ---
    va_kernel<<<9, 256, 0, stream>>>(w_efft, b_eff, as1, ad1, b1, va, cvec, b1s);

    auto gemm_grid = [&](int NB) { return 8 * XT * NB; };

    // --- layer 1, aggregated in input space ---
    es1_kernel<<<n, 64, 0, stream>>>(x_bf, va, cvec, es, ed);
    agg1x_kernel<<<n, 256, 0, stream>>>(x_bf, es, ed, csr, off, z_bf);
    // act = ELU( z @ W_eff(per-head) + b_eff + b1 )
    gemm_bf16_kernel<<<gemm_grid(16), 256, 0, stream>>>(
        z_bf, w_efft, b1s, act_bf, n, 2048, 256, 1024, 256, 1, MB, 16, XT);

    // --- layer 2 (H=4, concat, ELU) ---
    gemm_bf16_kernel<<<gemm_grid(16), 256, 0, stream>>>(
        act_bf, w2t, nullptr, h_bf, n, 2048, 2048, 2048, 0, 0, MB, 16, XT);
    esed_kernel<<<n, 4 * 64, 0, stream>>>(h_bf, as2, ad2, es, ed, 4);
    agg_kernel<4, 8, false><<<n, 256, 0, stream>>>(h_bf, es, ed, csr, off, b2,
                                                   nullptr, act_bf, 1);

    // --- layer 3 (H=2, mean+bias fused, no ELU) ---
    gemm_bf16_kernel<<<gemm_grid(8), 256, 0, stream>>>(
        act_bf, w3t, nullptr, h_bf, n, 1024, 2048, 2048, 0, 0, MB, 8, XT);
    esed_kernel<<<n, 2 * 64, 0, stream>>>(h_bf, as3, ad3, es, ed, 2);
    agg_kernel<2, 4, true><<<n, 256, 0, stream>>>(h_bf, es, ed, csr, off, b3,
                                                  (float*)d_out, nullptr, 0);
}

// Round 10
// 632.421 us; speedup vs baseline: 1.1762x; 1.0046x over previous
//
#include <hip/hip_runtime.h>
#include <hip/hip_bf16.h>
#include <math.h>

#define CDIV(a,b) (((a)+(b)-1)/(b))

typedef __bf16  bf16x8 __attribute__((ext_vector_type(8)));
typedef float   f32x4  __attribute__((ext_vector_type(4)));
typedef unsigned short u16x8 __attribute__((ext_vector_type(8)));
typedef unsigned short u16x4 __attribute__((ext_vector_type(4)));

__device__ __forceinline__ float bf2f(unsigned short u) {
    union { unsigned int i; float f; } x; x.i = ((unsigned int)u) << 16; return x.f;
}
__device__ __forceinline__ unsigned short f2bf(float f) {
    union { float f; unsigned int i; } x; x.f = f;
    unsigned int r = x.i + 0x7fff + ((x.i >> 16) & 1);   // RNE, finite inputs
    return (unsigned short)(r >> 16);
}

// ---------------------------------------------------------------------------
// CSR build (by destination node). Edges = [E graph edges] + [n self-loops].
// ---------------------------------------------------------------------------
__global__ void hist_kernel(const int* __restrict__ ei, int* __restrict__ deg,
                            int E, int Et) {
    int e = blockIdx.x * blockDim.x + threadIdx.x;
    if (e >= Et) return;
    int d = (e < E) ? ei[E + e] : (e - E);
    atomicAdd(&deg[d], 1);
}

// Single-block exclusive scan, wave-shuffle based.
__global__ void scan_kernel(const int* __restrict__ deg, int* __restrict__ off, int n) {
    __shared__ int wsum[16];
    __shared__ int carry_s;
    int t = threadIdx.x, lane = t & 63, wv = t >> 6;
    if (t == 0) carry_s = 0;
    __syncthreads();
    for (int base = 0; base < n; base += 1024) {
        int v = (base + t < n) ? deg[base + t] : 0;
        int x = v;
#pragma unroll
        for (int o = 1; o < 64; o <<= 1) {
            int y = __shfl_up(x, o);
            if (lane >= o) x += y;
        }
        if (lane == 63) wsum[wv] = x;
        __syncthreads();
        if (wv == 0 && lane < 16) {
            int s = wsum[lane];
#pragma unroll
            for (int o = 1; o < 16; o <<= 1) {
                int y = __shfl_up(s, o);
                if (lane >= o) s += y;
            }
            wsum[lane] = s;
        }
        __syncthreads();
        int wprev = (wv == 0) ? 0 : wsum[wv - 1];
        int incl = carry_s + wprev + x;
        if (base + t < n) off[base + t] = incl - v;
        __syncthreads();
        if (t == 1023) carry_s = incl;
        __syncthreads();
    }
    if (t == 0) off[n] = carry_s;
}

__global__ void scatter_kernel(const int* __restrict__ ei, const int* __restrict__ off,
                               int* __restrict__ cur, int* __restrict__ csr,
                               int E, int Et) {
    int e = blockIdx.x * blockDim.x + threadIdx.x;
    if (e >= Et) return;
    int s, d;
    if (e < E) { s = ei[e]; d = ei[E + e]; } else { s = e - E; d = s; }
    int pos = off[d] + atomicAdd(&cur[d], 1);
    csr[pos] = s;
}

// ---------------------------------------------------------------------------
// Fused weight transpose+cvt: 3 jobs in one launch, 32x32 tiles.
// ---------------------------------------------------------------------------
__global__ void prep_t_kernel(const float* __restrict__ wa, __hip_bfloat16* __restrict__ wta,
                              const float* __restrict__ wb, __hip_bfloat16* __restrict__ wtb,
                              const float* __restrict__ wc, __hip_bfloat16* __restrict__ wtc,
                              int t0, int t1, int t2) {
    __shared__ float tile[32][33];
    int bid = blockIdx.x;
    const float* w; __hip_bfloat16* wt; int K, N, r;
    if (bid < t0)      { w = wa; wt = wta; K = 512;  N = 2048; r = bid; }
    else if (bid < t1) { w = wb; wt = wtb; K = 2048; N = 2048; r = bid - t0; }
    else               { w = wc; wt = wtc; K = 2048; N = 1024; r = bid - t1; }
    (void)t2;
    int kt = K >> 5;
    int kb = (r % kt) * 32, nb = (r / kt) * 32;
    int tx = threadIdx.x & 31, ty = threadIdx.x >> 5;
    for (int i = ty; i < 32; i += 8)
        tile[i][tx] = w[(size_t)(kb + i) * N + nb + tx];
    __syncthreads();
    for (int i = ty; i < 32; i += 8)
        wt[(size_t)(nb + i) * K + kb + tx] = __float2bfloat16(tile[tx][i]);
}

// Fused fp32->bf16 convert of proj_w then x (both sizes %4 == 0).
__global__ void cvt2_kernel(const float* __restrict__ a, __hip_bfloat16* __restrict__ ao,
                            int na4,
                            const float* __restrict__ b, __hip_bfloat16* __restrict__ bo,
                            int nb4) {
    int i = blockIdx.x * blockDim.x + threadIdx.x;
    const float* src; __hip_bfloat16* dst; int idx;
    if (i < na4) { src = a; dst = ao; idx = i * 4; }
    else if (i < na4 + nb4) { src = b; dst = bo; idx = (i - na4) * 4; }
    else return;
    float4 v = *(const float4*)(src + idx);
    dst[idx + 0] = __float2bfloat16(v.x);
    dst[idx + 1] = __float2bfloat16(v.y);
    dst[idx + 2] = __float2bfloat16(v.z);
    dst[idx + 3] = __float2bfloat16(v.w);
}

// b_eff[j] += partial over k-chunk of proj_b[k]*w1[k][j] (k-split, unrolled).
__global__ void beff_kernel(const float* __restrict__ pb, const float* __restrict__ w1,
                            float* __restrict__ beff, int N) {
    int j  = blockIdx.x * 256 + threadIdx.x;
    int k0 = blockIdx.y * 64;
    float s = 0.f;
#pragma unroll
    for (int k = 0; k < 64; k++)
        s = fmaf(pb[k0 + k], w1[(size_t)(k0 + k) * N + j], s);
    atomicAdd(&beff[j], s);
}

// ---------------------------------------------------------------------------
// va[j][256] = W_eff[:, head-block j] @ a_vec   (j<4: a_src head j; j>=4: a_dst)
// cvec[j] = b_eff[head-block] . a_vec ;  block 8 computes b1s = b_eff + b1.
// ---------------------------------------------------------------------------
__global__ void va_kernel(const __hip_bfloat16* __restrict__ w_efft,
                          const float* __restrict__ b_eff,
                          const float* __restrict__ as1, const float* __restrict__ ad1,
                          const float* __restrict__ b1,
                          float* __restrict__ va, float* __restrict__ cvec,
                          float* __restrict__ b1s) {
    int j = blockIdx.x, t = threadIdx.x;
    if (j == 8) {
        for (int i = t; i < 2048; i += 256) b1s[i] = b_eff[i] + b1[i];
        return;
    }
    int h = j & 3;
    const float* a = ((j < 4) ? as1 : ad1) + h * 512;
    __shared__ float aLDS[512];
    __shared__ float red[256];
    for (int c = t; c < 512; c += 256) aLDS[c] = a[c];
    __syncthreads();
    float acc = 0.f;
    const unsigned short* wb = (const unsigned short*)w_efft + (size_t)h * 512 * 256 + t;
    for (int c = 0; c < 512; c++)
        acc = fmaf(aLDS[c], bf2f(wb[(size_t)c * 256]), acc);
    va[j * 256 + t] = acc;
    float cp = b_eff[h * 512 + t] * aLDS[t] + b_eff[h * 512 + 256 + t] * aLDS[256 + t];
    red[t] = cp;
    __syncthreads();
    for (int s = 128; s > 0; s >>= 1) {
        if (t < s) red[t] += red[t + s];
        __syncthreads();
    }
    if (t == 0) cvec[j] = red[0];
}

// ---------------------------------------------------------------------------
// es1/ed1: es[node][h] = x_bf[node] . va[h] + cvec[h]  (one wave per node).
// ---------------------------------------------------------------------------
__global__ void es1_kernel(const __hip_bfloat16* __restrict__ x_bf,
                           const float* __restrict__ va, const float* __restrict__ cvec,
                           float* __restrict__ es, float* __restrict__ ed) {
    int node = blockIdx.x, l = threadIdx.x;
    u16x4 xv = *(const u16x4*)((const unsigned short*)x_bf + (size_t)node * 256 + l * 4);
    float xf[4];
#pragma unroll
    for (int k = 0; k < 4; k++) xf[k] = bf2f(xv[k]);
    float dot[8];
#pragma unroll
    for (int j = 0; j < 8; j++) {
        float4 v = *(const float4*)(va + j * 256 + l * 4);
        dot[j] = xf[0] * v.x + xf[1] * v.y + xf[2] * v.z + xf[3] * v.w;
    }
#pragma unroll
    for (int j = 0; j < 8; j++)
        for (int o = 32; o; o >>= 1) dot[j] += __shfl_down(dot[j], o);
    if (l == 0) {
#pragma unroll
        for (int h = 0; h < 4; h++) {
            es[node * 4 + h] = dot[h] + cvec[h];
            ed[node * 4 + h] = dot[4 + h] + cvec[4 + h];
        }
    }
}

// ---------------------------------------------------------------------------
// Layer-1 aggregation in INPUT space (256 ch): one block per dst.
// ---------------------------------------------------------------------------
__global__ __launch_bounds__(256) void agg1x_kernel(
    const __hip_bfloat16* __restrict__ x_bf, const float* __restrict__ es,
    const float* __restrict__ ed, const int* __restrict__ csr,
    const int* __restrict__ off, __hip_bfloat16* __restrict__ z)
{
    __shared__ float alds[64][4];
    __shared__ int   slds[64];
    int d = blockIdx.x, t = threadIdx.x;
    int beg = off[d], end = off[d + 1];
    float acc[4] = {0.f, 0.f, 0.f, 0.f}, den[4] = {0.f, 0.f, 0.f, 0.f};
    float edd[4];
#pragma unroll
    for (int h = 0; h < 4; h++) edd[h] = ed[d * 4 + h];
    const unsigned short* xb = (const unsigned short*)x_bf;

    for (int cb = beg; cb < end; cb += 64) {
        int cl = end - cb; if (cl > 64) cl = 64;
        int i = t >> 2, h = t & 3;
        if (i < cl) {
            int s = csr[cb + i];
            if (h == 0) slds[i] = s;
            float e = es[s * 4 + h] + edd[h];
            e = (e > 0.f) ? e : 0.2f * e;
            alds[i][h] = __expf(e);
        }
        __syncthreads();
        for (int ii = 0; ii < cl; ii++) {
            int s = slds[ii];
            float xv = bf2f(xb[(size_t)s * 256 + t]);
#pragma unroll
            for (int hh = 0; hh < 4; hh++) {
                float a = alds[ii][hh];
                den[hh] += a;
                acc[hh] = fmaf(a, xv, acc[hh]);
            }
        }
        __syncthreads();
    }
    unsigned short* zb = (unsigned short*)z + (size_t)d * 1024;
#pragma unroll
    for (int h = 0; h < 4; h++)
        zb[h * 256 + t] = f2bf(acc[h] / den[h]);
}

// ---------------------------------------------------------------------------
// bf16 MFMA GEMM: Cb[M,N] = bf16(act( A[M,K(lda)] @ BT[N,K]^T + bias ))
// 128x128 tile, BK=32, 256 threads (4 waves), 16x16x32 MFMA.
// Intra-XCD swizzle (R10): slot -> (yh outer, x_sub mid, ys inner) with NBH
// y-tiles per phase, so the ~70 concurrently-resident blocks per XCD share a
// B working set of NBH*512KB (<= 4MB L2) instead of cycling the full B.
// lda = A row stride; hko != 0 -> A col base += (n0>>9)*hko. do_elu: epilogue.
// NOTE (R7): never fuse cross-XCD atomic reductions into this epilogue.
// ---------------------------------------------------------------------------
__device__ __forceinline__ void gload16(void* lds, const void* g) {
    __builtin_amdgcn_global_load_lds(
        (const __attribute__((address_space(1))) void*)g,
        (__attribute__((address_space(3))) void*)lds, 16, 0, 0);
}

__global__ __launch_bounds__(256) void gemm_bf16_kernel(
    const __hip_bfloat16* __restrict__ A,
    const __hip_bfloat16* __restrict__ BT,
    const float* __restrict__ bias,
    __hip_bfloat16* __restrict__ Cb,
    int M, int N, int K, int lda, int hko, int do_elu,
    int MB, int NB, int XT, int NBH)
{
    __shared__ __align__(16) __hip_bfloat16 As[128 * 32];
    __shared__ __align__(16) __hip_bfloat16 Bs[128 * 32];

    const int bid  = blockIdx.x;
    const int xcd  = bid & 7;
    const int slot = bid >> 3;
    const int per_yh = XT * NBH;
    const int yh    = slot / per_yh;
    const int rem   = slot - yh * per_yh;
    const int x_sub = rem / NBH;
    const int ys    = rem - x_sub * NBH;
    const int yb    = yh * NBH + ys;
    const int xb    = xcd * XT + x_sub;
    if (xb >= MB || yb >= NB) return;

    const int tid = threadIdx.x;
    const int m0 = xb * 128, n0 = yb * 128;
    const int w = tid >> 6, l = tid & 63;
    const int wm = (w & 1) * 64, wn = (w >> 1) * 64;
    const int lm = l & 15, lq = l >> 4;

    f32x4 acc[4][4] = {};

    const int arow = tid >> 2;
    const int acol = (tid & 3) * 8;
    const __hip_bfloat16* Ag = A + (size_t)(m0 + arow) * lda + acol + (n0 >> 9) * hko;
    const __hip_bfloat16* Bg = BT + (size_t)(n0 + arow) * K + acol;
    char* AsW = (char*)As + (w << 10);
    char* BsW = (char*)Bs + (w << 10);

    for (int k0 = 0; k0 < K; k0 += 32) {
        gload16(AsW,        Ag + k0);
        gload16(AsW + 4096, Ag + (size_t)64 * lda + k0);
        gload16(BsW,        Bg + k0);
        gload16(BsW + 4096, Bg + (size_t)64 * K + k0);
        __syncthreads();
        bf16x8 af[4], bfr[4];
#pragma unroll
        for (int i = 0; i < 4; i++)
            af[i] = *(const bf16x8*)(As + (wm + i * 16 + lm) * 32 + lq * 8);
#pragma unroll
        for (int j = 0; j < 4; j++)
            bfr[j] = *(const bf16x8*)(Bs + (wn + j * 16 + lm) * 32 + lq * 8);
#pragma unroll
        for (int i = 0; i < 4; i++)
#pragma unroll
            for (int j = 0; j < 4; j++)
                acc[i][j] = __builtin_amdgcn_mfma_f32_16x16x32_bf16(
                    af[i], bfr[j], acc[i][j], 0, 0, 0);
        __syncthreads();
    }

#pragma unroll
    for (int i = 0; i < 4; i++) {
        int rb = m0 + wm + i * 16 + lq * 4;
#pragma unroll
        for (int r = 0; r < 4; r++) {
            int row = rb + r;
            if (row >= M) continue;
#pragma unroll
            for (int j = 0; j < 4; j++) {
                int col = n0 + wn + j * 16 + lm;
                float v = acc[i][j][r];
                if (bias) v += bias[col];
                if (do_elu) v = (v > 0.f) ? v : expm1f(v);
                Cb[(size_t)row * N + col] = __float2bfloat16(v);
            }
        }
    }
}

// ---------------------------------------------------------------------------
// es/ed: per-node per-head dot with a_src/a_dst (h in bf16). One wave/head.
// ---------------------------------------------------------------------------
__global__ void esed_kernel(const __hip_bfloat16* __restrict__ h,
                            const float* __restrict__ a_src,
                            const float* __restrict__ a_dst,
                            float* __restrict__ es, float* __restrict__ ed, int H) {
    int nidx = blockIdx.x;
    int t = threadIdx.x;
    int head = t >> 6, lane = t & 63;
    const unsigned short* hp =
        (const unsigned short*)h + (size_t)nidx * H * 512 + head * 512 + lane * 8;
    const float* sp = a_src + head * 512 + lane * 8;
    const float* dp = a_dst + head * 512 + lane * 8;
    u16x8 hv = *(const u16x8*)hp;
    float4 s0 = *(const float4*)sp, s1 = *(const float4*)(sp + 4);
    float4 d0 = *(const float4*)dp, d1 = *(const float4*)(dp + 4);
    float hf[8];
#pragma unroll
    for (int k = 0; k < 8; k++) hf[k] = bf2f(hv[k]);
    float s = hf[0]*s0.x + hf[1]*s0.y + hf[2]*s0.z + hf[3]*s0.w
            + hf[4]*s1.x + hf[5]*s1.y + hf[6]*s1.z + hf[7]*s1.w;
    float d = hf[0]*d0.x + hf[1]*d0.y + hf[2]*d0.z + hf[3]*d0.w
            + hf[4]*d1.x + hf[5]*d1.y + hf[6]*d1.z + hf[7]*d1.w;
    for (int o = 32; o; o >>= 1) { s += __shfl_down(s, o); d += __shfl_down(d, o); }
    if (lane == 0) { es[nidx * H + head] = s; ed[nidx * H + head] = d; }
}

// ---------------------------------------------------------------------------
// Aggregation (layers 2/3): ONE block per dst, all heads. Thread t owns
// channels [t*VEC, t*VEC+VEC). 4x edge unroll. MEAN variant fuses mean+bias.
// ---------------------------------------------------------------------------
template<int H, int VEC, bool MEAN>
__global__ __launch_bounds__(256) void agg_kernel(
    const __hip_bfloat16* __restrict__ h, const float* __restrict__ es,
    const float* __restrict__ ed, const int* __restrict__ csr,
    const int* __restrict__ off, const float* __restrict__ bias,
    float* __restrict__ outF, __hip_bfloat16* __restrict__ outB, int do_elu)
{
    constexpr int HS = H * 512;
    __shared__ float red[MEAN ? 1024 : 1];
    int d = blockIdx.x, t = threadIdx.x;
    int c0 = t * VEC;
    int head = c0 >> 9;
    float edd = ed[d * H + head];
    int beg = off[d], end = off[d + 1];
    float acc[VEC];
#pragma unroll
    for (int k = 0; k < VEC; k++) acc[k] = 0.f;
    float den = 0.f;
    const unsigned short* hb = (const unsigned short*)h;

    int i = beg;
    for (; i + 3 < end; i += 4) {
        int   s[4];
        float wgt[4];
#pragma unroll
        for (int u = 0; u < 4; u++) {
            s[u] = csr[i + u];
            float e = es[s[u] * H + head] + edd;
            e = (e > 0.f) ? e : 0.2f * e;
            wgt[u] = __expf(e);
        }
        if constexpr (VEC == 8) {
            u16x8 v[4];
#pragma unroll
            for (int u = 0; u < 4; u++)
                v[u] = *(const u16x8*)(hb + (size_t)s[u] * HS + c0);
#pragma unroll
            for (int u = 0; u < 4; u++) {
                den += wgt[u];
#pragma unroll
                for (int k = 0; k < 8; k++) acc[k] = fmaf(wgt[u], bf2f(v[u][k]), acc[k]);
            }
        } else {
            u16x4 v[4];
#pragma unroll
            for (int u = 0; u < 4; u++)
                v[u] = *(const u16x4*)(hb + (size_t)s[u] * HS + c0);
#pragma unroll
            for (int u = 0; u < 4; u++) {
                den += wgt[u];
#pragma unroll
                for (int k = 0; k < VEC; k++) acc[k] = fmaf(wgt[u], bf2f(v[u][k]), acc[k]);
            }
        }
    }
    for (; i < end; i++) {
        int s0 = csr[i];
        float e0 = es[s0 * H + head] + edd;
        e0 = (e0 > 0.f) ? e0 : 0.2f * e0;
        float w0 = __expf(e0);
        den += w0;
        const unsigned short* hp0 = hb + (size_t)s0 * HS + c0;
        if constexpr (VEC == 8) {
            u16x8 v0 = *(const u16x8*)hp0;
#pragma unroll
            for (int k = 0; k < 8; k++) acc[k] = fmaf(w0, bf2f(v0[k]), acc[k]);
        } else {
            u16x4 v0 = *(const u16x4*)hp0;
#pragma unroll
            for (int k = 0; k < VEC; k++) acc[k] = fmaf(w0, bf2f(v0[k]), acc[k]);
        }
    }

    float inv = 1.f / den;
    if constexpr (!MEAN) {
        u16x8 ov;
#pragma unroll
        for (int k = 0; k < VEC; k++) {
            float v = acc[k] * inv + bias[c0 + k];
            if (do_elu) v = (v > 0.f) ? v : expm1f(v);
            ov[k] = f2bf(v);
        }
        *(u16x8*)((unsigned short*)outB + (size_t)d * HS + c0) = ov;
    } else {
#pragma unroll
        for (int k = 0; k < VEC; k++) red[c0 + k] = acc[k] * inv;
        __syncthreads();
        if (t < 128) {
#pragma unroll
            for (int k = 0; k < 4; k++) {
                int c = t * 4 + k;
                outF[(size_t)d * 512 + c] = 0.5f * (red[c] + red[c + 512]) + bias[c];
            }
        }
    }
}

// ---------------------------------------------------------------------------
extern "C" void kernel_launch(void* const* d_in, const int* in_sizes, int n_in,
                              void* d_out, int out_size, void* d_ws, size_t ws_size,
                              hipStream_t stream) {
    const float* x      = (const float*)d_in[0];
    const int*   ei     = (const int*)  d_in[1];
    const float* proj_w = (const float*)d_in[2];
    const float* proj_b = (const float*)d_in[3];
    const float* w1  = (const float*)d_in[4];
    const float* as1 = (const float*)d_in[5];
    const float* ad1 = (const float*)d_in[6];
    const float* b1  = (const float*)d_in[7];
    const float* w2  = (const float*)d_in[8];
    const float* as2 = (const float*)d_in[9];
    const float* ad2 = (const float*)d_in[10];
    const float* b2  = (const float*)d_in[11];
    const float* w3  = (const float*)d_in[12];
    const float* as3 = (const float*)d_in[13];
    const float* ad3 = (const float*)d_in[14];
    const float* b3  = (const float*)d_in[15];

    const int n    = in_sizes[0] / 256;   // 10000
    const int E    = in_sizes[1] / 2;     // 160000
    const int Et   = E + n;               // 170000
    const int MB   = CDIV(n, 128);        // 79
    const int Mpad = MB * 128;            // 10112
    const int XT   = CDIV(MB, 8);         // 10

    char* p = (char*)d_ws;
    auto carve = [&](size_t bytes) {
        void* r = (void*)p;
        p += (bytes + 255) & ~(size_t)255;
        return r;
    };
    __hip_bfloat16* h_bf    = (__hip_bfloat16*)carve((size_t)Mpad * 2048 * sizeof(__hip_bfloat16));
    __hip_bfloat16* act_bf  = (__hip_bfloat16*)carve((size_t)Mpad * 2048 * sizeof(__hip_bfloat16));
    __hip_bfloat16* x_bf    = (__hip_bfloat16*)carve((size_t)Mpad * 256 * sizeof(__hip_bfloat16));
    __hip_bfloat16* pw_bf   = (__hip_bfloat16*)carve((size_t)256 * 512 * sizeof(__hip_bfloat16));
    __hip_bfloat16* w1t     = (__hip_bfloat16*)carve((size_t)2048 * 512 * sizeof(__hip_bfloat16));
    __hip_bfloat16* w2t     = (__hip_bfloat16*)carve((size_t)2048 * 2048 * sizeof(__hip_bfloat16));
    __hip_bfloat16* w3t     = (__hip_bfloat16*)carve((size_t)1024 * 2048 * sizeof(__hip_bfloat16));
    __hip_bfloat16* w_efft  = (__hip_bfloat16*)carve((size_t)2048 * 256 * sizeof(__hip_bfloat16));
    float* b_eff = (float*)carve((size_t)2048 * sizeof(float));
    float* b1s   = (float*)carve((size_t)2048 * sizeof(float));
    float* va    = (float*)carve((size_t)8 * 256 * sizeof(float));
    float* cvec  = (float*)carve((size_t)8 * sizeof(float));
    float* es  = (float*)carve((size_t)n * 4 * sizeof(float));
    float* ed  = (float*)carve((size_t)n * 4 * sizeof(float));
    int* deg = (int*)carve((size_t)2 * n * sizeof(int));   // deg + cur contiguous
    int* cur = deg + n;
    int* off = (int*)carve((size_t)(n + 1) * sizeof(int));
    int* csr = (int*)carve((size_t)Et * sizeof(int));
    __hip_bfloat16* z_bf = h_bf;   // layer-1 aggregated-x [Mpad,1024], overlays h_bf
    (void)ws_size; (void)n_in;

    // --- CSR build ---
    hipMemsetAsync(deg, 0, 2 * n * sizeof(int), stream);
    hipMemsetAsync(b_eff, 0, 2048 * sizeof(float), stream);
    hist_kernel<<<CDIV(Et, 256), 256, 0, stream>>>(ei, deg, E, Et);
    scan_kernel<<<1, 1024, 0, stream>>>(deg, off, n);
    scatter_kernel<<<CDIV(Et, 256), 256, 0, stream>>>(ei, off, cur, csr, E, Et);

    // --- weight prep (fused) ---
    const int t0 = (512 / 32) * (2048 / 32);            // 1024
    const int t1 = t0 + (2048 / 32) * (2048 / 32);      // +4096
    const int t2 = t1 + (2048 / 32) * (1024 / 32);      // +2048
    prep_t_kernel<<<t2, 256, 0, stream>>>(w1, w1t, w2, w2t, w3, w3t, t0, t1, t2);
    const int na4 = 256 * 512 / 4, nb4 = n * 256 / 4;
    cvt2_kernel<<<CDIV(na4 + nb4, 256), 256, 0, stream>>>(proj_w, pw_bf, na4, x, x_bf, nb4);

    // --- fold proj into layer 1: W_eff^T[2048,256]; b_eff = proj_b @ w1 ---
    gemm_bf16_kernel<<<8 * 2 * 2, 256, 0, stream>>>(
        w1t, pw_bf, nullptr, w_efft, 2048, 256, 512, 512, 0, 0, 16, 2, 2, 2);
    beff_kernel<<<dim3(2048 / 256, 512 / 64), 256, 0, stream>>>(proj_b, w1, b_eff, 2048);

    // --- layer-1 attention vectors + constants; b1s = b_eff + b1 ---
    va_kernel<<<9, 256, 0, stream>>>(w_efft, b_eff, as1, ad1, b1, va, cvec, b1s);

    auto gemm_grid = [&](int NB) { return 8 * XT * NB; };

    // --- layer 1, aggregated in input space ---
    es1_kernel<<<n, 64, 0, stream>>>(x_bf, va, cvec, es, ed);
    agg1x_kernel<<<n, 256, 0, stream>>>(x_bf, es, ed, csr, off, z_bf);
    // act = ELU( z @ W_eff(per-head) + b_eff + b1 )   (B = 1MB, L2-fits: NBH=16)
    gemm_bf16_kernel<<<gemm_grid(16), 256, 0, stream>>>(
        z_bf, w_efft, b1s, act_bf, n, 2048, 256, 1024, 256, 1, MB, 16, XT, 16);

    // --- layer 2 (H=4, concat, ELU): B = 8MB -> NBH=8 (4MB L2 phases) ---
    gemm_bf16_kernel<<<gemm_grid(16), 256, 0, stream>>>(
        act_bf, w2t, nullptr, h_bf, n, 2048, 2048, 2048, 0, 0, MB, 16, XT, 8);
    esed_kernel<<<n, 4 * 64, 0, stream>>>(h_bf, as2, ad2, es, ed, 4);
    agg_kernel<4, 8, false><<<n, 256, 0, stream>>>(h_bf, es, ed, csr, off, b2,
                                                   nullptr, act_bf, 1);

    // --- layer 3 (H=2, mean+bias fused): B = 4MB -> NBH=4 (2MB L2 phases) ---
    gemm_bf16_kernel<<<gemm_grid(8), 256, 0, stream>>>(
        act_bf, w3t, nullptr, h_bf, n, 1024, 2048, 2048, 0, 0, MB, 8, XT, 4);
    esed_kernel<<<n, 2 * 64, 0, stream>>>(h_bf, as3, ad3, es, ed, 2);
    agg_kernel<2, 4, true><<<n, 256, 0, stream>>>(h_bf, es, ed, csr, off, b3,
                                                  (float*)d_out, nullptr, 0);
}